// Round 5
// baseline (594.791 us; speedup 1.0000x reference)
//
#include <hip/hip_runtime.h>

// Problem constants: B=2, T=2048, D=768, H=12, HD=64
#define B_  2
#define T_  2048
#define D_  768
#define H_  12
#define HD_ 64

typedef short bf16x8 __attribute__((ext_vector_type(8)));   // 8 bf16 = 4 VGPR
typedef float f32x4  __attribute__((ext_vector_type(4)));   // MFMA 16x16 acc
typedef unsigned int u32;

static __device__ __forceinline__ unsigned short f2bf(float f) {
    union { float f; unsigned u; } v; v.f = f;
    unsigned r = (v.u + 0x7FFFu + ((v.u >> 16) & 1u)) >> 16;   // RNE
    return (unsigned short)r;
}

// ---------------------------------------------------------------------------
// fp32 -> bf16 convert, grid-stride, 8 elems/thread
// ---------------------------------------------------------------------------
__global__ void cvt_f32_bf16(const float* __restrict__ in,
                             unsigned short* __restrict__ out, int n8) {
    int i = blockIdx.x * blockDim.x + threadIdx.x;
    int stride = gridDim.x * blockDim.x;
    for (; i < n8; i += stride) {
        float4 a = *(const float4*)(in + (size_t)i * 8);
        float4 b = *(const float4*)(in + (size_t)i * 8 + 4);
        union { unsigned short s[8]; int4 v; } o;
        o.s[0] = f2bf(a.x); o.s[1] = f2bf(a.y); o.s[2] = f2bf(a.z); o.s[3] = f2bf(a.w);
        o.s[4] = f2bf(b.x); o.s[5] = f2bf(b.y); o.s[6] = f2bf(b.z); o.s[7] = f2bf(b.w);
        *(int4*)(out + (size_t)i * 8) = o.v;
    }
}

__global__ void cvt_weights(const float* __restrict__ w0, const float* __restrict__ w1,
                            const float* __restrict__ w2, const float* __restrict__ w3,
                            unsigned short* __restrict__ out, int n8) {
    const float* src = (blockIdx.y == 0) ? w0 : (blockIdx.y == 1) ? w1
                     : (blockIdx.y == 2) ? w2 : w3;
    unsigned short* dst = out + (size_t)blockIdx.y * (D_ * D_);
    int i = blockIdx.x * blockDim.x + threadIdx.x;
    int stride = gridDim.x * blockDim.x;
    for (; i < n8; i += stride) {
        float4 a = *(const float4*)(src + (size_t)i * 8);
        float4 b = *(const float4*)(src + (size_t)i * 8 + 4);
        union { unsigned short s[8]; int4 v; } o;
        o.s[0] = f2bf(a.x); o.s[1] = f2bf(a.y); o.s[2] = f2bf(a.z); o.s[3] = f2bf(a.w);
        o.s[4] = f2bf(b.x); o.s[5] = f2bf(b.y); o.s[6] = f2bf(b.z); o.s[7] = f2bf(b.w);
        *(int4*)(dst + (size_t)i * 8) = o.v;
    }
}

// ---------------------------------------------------------------------------
// bf16 MFMA GEMM, m97 geometry: BM=BN=128, BK=32, global_load_lds staging.
//   A: [4096][768] bf16; W: [NW][768] bf16 (NW = 2304 fused-QKV or 768)
//   mode 1: epilogue routes to q/k/v [B,H,T,HD] bf16 (scale on q section)
//   mode 0: fp32 out [4096][768] + bias
// 4 waves 2x2 (wave tile 64x64), 4x4 frags, 16 MFMA/iter. Linear LDS.
// ---------------------------------------------------------------------------
__global__ __launch_bounds__(256)
void gemm_bt_lds(const unsigned short* __restrict__ A,
                 const unsigned short* __restrict__ W,
                 const float* __restrict__ b0, const float* __restrict__ b1,
                 const float* __restrict__ b2,
                 void* __restrict__ outp, int mode)
{
    __shared__ __align__(16) unsigned short As[128 * 32];
    __shared__ __align__(16) unsigned short Bs[128 * 32];

    const int tid  = threadIdx.x;
    const int lane = tid & 63;
    const int wid  = tid >> 6;
    const int wm   = wid >> 1, wn = wid & 1;
    const int l15  = lane & 15, l16 = lane >> 4;
    const int bm   = blockIdx.x * 128, bn = blockIdx.y * 128;

    f32x4 acc[4][4];
    #pragma unroll
    for (int mi = 0; mi < 4; ++mi)
        #pragma unroll
        for (int ni = 0; ni < 4; ++ni)
            acc[mi][ni] = (f32x4){0.f, 0.f, 0.f, 0.f};

    const int srow = lane >> 2;           // 0..15 within chunk
    const int scol = (lane & 3) * 8;      // ushort offset of 16B chunk

    for (int k0 = 0; k0 < 768; k0 += 32) {
        // 16 x 1KB chunks (8 A + 8 B), 4 per wave, gload_lds width 16
        #pragma unroll
        for (int j = 0; j < 4; ++j) {
            int c = wid * 4 + j;
            const unsigned short* src;
            unsigned short* dst;
            if (c < 8) {
                src = A + (size_t)(bm + c * 16 + srow) * 768 + k0 + scol;
                dst = As + c * 512;
            } else {
                src = W + (size_t)(bn + (c - 8) * 16 + srow) * 768 + k0 + scol;
                dst = Bs + (c - 8) * 512;
            }
            __builtin_amdgcn_global_load_lds(
                (const __attribute__((address_space(1))) u32*)src,
                (__attribute__((address_space(3))) u32*)dst, 16, 0, 0);
        }
        __syncthreads();

        bf16x8 af[4], bfr[4];
        #pragma unroll
        for (int mi = 0; mi < 4; ++mi)
            af[mi] = *(const bf16x8*)(As + (wm * 64 + mi * 16 + l15) * 32 + l16 * 8);
        #pragma unroll
        for (int ni = 0; ni < 4; ++ni)
            bfr[ni] = *(const bf16x8*)(Bs + (wn * 64 + ni * 16 + l15) * 32 + l16 * 8);
        #pragma unroll
        for (int mi = 0; mi < 4; ++mi)
            #pragma unroll
            for (int ni = 0; ni < 4; ++ni)
                acc[mi][ni] = __builtin_amdgcn_mfma_f32_16x16x32_bf16(
                    af[mi], bfr[ni], acc[mi][ni], 0, 0, 0);
        __syncthreads();
    }

    // epilogue: C/D layout col = lane&15, row = (lane>>4)*4 + reg
    if (mode == 1) {
        const int sel = bn / 768;                       // 0=q 1=k 2=v (uniform)
        const float* bp = (sel == 0) ? b0 : (sel == 1) ? b1 : b2;
        const float scale = (sel == 0) ? 0.125f : 1.0f;
        unsigned short* o = (unsigned short*)outp + (size_t)sel * (B_ * T_ * D_);
        #pragma unroll
        for (int ni = 0; ni < 4; ++ni) {
            int cg = bn - sel * 768 + wn * 64 + ni * 16 + l15;
            float bv = bp[cg];
            int h = cg >> 6, hd = cg & 63;
            #pragma unroll
            for (int mi = 0; mi < 4; ++mi)
                #pragma unroll
                for (int reg = 0; reg < 4; ++reg) {
                    int row = bm + wm * 64 + mi * 16 + l16 * 4 + reg;
                    int bb = row >> 11, t = row & (T_ - 1);
                    float v = (acc[mi][ni][reg] + bv) * scale;
                    o[(((size_t)bb * H_ + h) * T_ + t) * HD_ + hd] = f2bf(v);
                }
        }
    } else {
        float* o = (float*)outp;
        #pragma unroll
        for (int ni = 0; ni < 4; ++ni) {
            int col = bn + wn * 64 + ni * 16 + l15;
            float bv = b0[col];
            #pragma unroll
            for (int mi = 0; mi < 4; ++mi)
                #pragma unroll
                for (int reg = 0; reg < 4; ++reg) {
                    int row = bm + wm * 64 + mi * 16 + l16 * 4 + reg;
                    o[(size_t)row * 768 + col] = acc[mi][ni][reg] + bv;
                }
        }
    }
}

// ---------------------------------------------------------------------------
// Flash attention v4b: 512 threads = 2 key-split groups x 4 waves x 16 q-rows.
//   Group g handles keys [g*1024, g*1024+1024); partial (m,l,o) merged at end.
//   K read DIRECT from global (L2/L3-hot); V transposed into dbuf LDS;
//   bias/mask + V prefetched one tile ahead; defer-max rescale (THR=8).
//   P tiles are PER-WAVE LDS slices (v4 had a per-group race here).
// ---------------------------------------------------------------------------
__global__ __launch_bounds__(512, 4)
void attn_fwd_mfma(const unsigned short* __restrict__ q,
                   const unsigned short* __restrict__ k,
                   const unsigned short* __restrict__ v,
                   const float* __restrict__ bias,
                   const float* __restrict__ mask,
                   unsigned short* __restrict__ ctx)
{
    // LDS plan (bytes): Vt[4] = (g*2+buf)*8704 at 0..34816; P[8 waves] at 34816..52224
    // merge overlay (after loop): Osh[64][65] at 0, Msh at 16640, Lsh at 16896
    __shared__ __align__(16) unsigned char Lraw[52224];
    unsigned short* VtBuf = (unsigned short*)Lraw;
    unsigned short* PsBuf = (unsigned short*)(Lraw + 34816);
    float* Osh = (float*)Lraw;
    float* Msh = (float*)(Lraw + 16640);
    float* Lsh = (float*)(Lraw + 16896);

    const int tid  = threadIdx.x;
    const int lane = tid & 63;
    const int wid  = tid >> 6;          // 0..7
    const int g    = wid >> 2;          // key-half group
    const int wq   = wid & 3;           // q-strip within group
    const int l15  = lane & 15, l16 = lane >> 4;
    const int bh   = blockIdx.y;
    const int b    = bh / H_, h = bh % H_;
    const int q0   = blockIdx.x * 64;

    const unsigned short* qb = q + (size_t)bh * T_ * HD_;
    const unsigned short* kb = k + (size_t)bh * T_ * HD_;
    const unsigned short* vb = v + (size_t)bh * T_ * HD_;

    unsigned short* Vt0 = VtBuf + (g * 2 + 0) * 4352;   // 64*68 ushorts
    unsigned short* Vt1 = VtBuf + (g * 2 + 1) * 4352;
    unsigned short* Pw  = PsBuf + wid * 1088;           // PER-WAVE 16*68 slice

    // Q fragment (B-operand of swapped mfma): q-row = lane&15, d = (lane>>4)*8+j
    bf16x8 qf[2];
    {
        const unsigned short* qp = qb + (size_t)(q0 + wq * 16 + l15) * HD_;
        qf[0] = *(const bf16x8*)(qp + l16 * 8);
        qf[1] = *(const bf16x8*)(qp + 32 + l16 * 8);
    }

    float m_run = -3.0e38f, l_run = 0.f;
    f32x4 o[4];
    #pragma unroll
    for (int f = 0; f < 4; ++f) o[f] = (f32x4){0.f, 0.f, 0.f, 0.f};

    const size_t brow = (size_t)h * T_ * T_ + (size_t)(q0 + wq * 16 + l15) * T_;
    const size_t mrow = (size_t)b * T_ * T_ + (size_t)(q0 + wq * 16 + l15) * T_;

    // group-local V staging slots: 256 threads x 2 int4 cover 64x64 ushorts
    const int tg   = tid & 255;
    const int vkey = tg & 63, vhd0 = (tg >> 6) * 8;

    int s0 = g * 1024;
    int4 vr0 = *(const int4*)(vb + (size_t)(s0 + vkey) * HD_ + vhd0);
    int4 vr1 = *(const int4*)(vb + (size_t)(s0 + vkey) * HD_ + vhd0 + 32);
    float4 bv4[4], mv4[4];
    #pragma unroll
    for (int f = 0; f < 4; ++f) {
        bv4[f] = *(const float4*)(bias + brow + s0 + f * 16 + l16 * 4);
        mv4[f] = *(const float4*)(mask + mrow + s0 + f * 16 + l16 * 4);
    }

    for (int i = 0; i < 16; ++i, s0 += 64) {
        unsigned short* Vtc = (i & 1) ? Vt1 : Vt0;
        {   // write current V tile (transposed) from prefetch regs
            const unsigned short* a = (const unsigned short*)&vr0;
            const unsigned short* c = (const unsigned short*)&vr1;
            #pragma unroll
            for (int e = 0; e < 8; ++e) {
                Vtc[(vhd0 + e) * 68 + vkey]      = a[e];
                Vtc[(vhd0 + 32 + e) * 68 + vkey] = c[e];
            }
        }
        if (i < 15) {   // prefetch next V tile
            vr0 = *(const int4*)(vb + (size_t)(s0 + 64 + vkey) * HD_ + vhd0);
            vr1 = *(const int4*)(vb + (size_t)(s0 + 64 + vkey) * HD_ + vhd0 + 32);
        }
        __syncthreads();   // b1: Vtc ready; prev PV (all waves) complete

        // ---- S^T = mfma(K, Q), K direct from global (L2-hot) ----
        f32x4 s[4];
        #pragma unroll
        for (int f = 0; f < 4; ++f) {
            bf16x8 k0f = *(const bf16x8*)(kb + (size_t)(s0 + f * 16 + l15) * HD_ + l16 * 8);
            bf16x8 k1f = *(const bf16x8*)(kb + (size_t)(s0 + f * 16 + l15) * HD_ + 32 + l16 * 8);
            f32x4 t = (f32x4){0.f, 0.f, 0.f, 0.f};
            t = __builtin_amdgcn_mfma_f32_16x16x32_bf16(k0f, qf[0], t, 0, 0, 0);
            t = __builtin_amdgcn_mfma_f32_16x16x32_bf16(k1f, qf[1], t, 0, 0, 0);
            s[f] = t;
        }

        // bias + mask from prefetch regs: key = f*16 + l16*4 + reg
        #pragma unroll
        for (int f = 0; f < 4; ++f) {
            const float* pb = (const float*)&bv4[f];
            const float* pm = (const float*)&mv4[f];
            #pragma unroll
            for (int reg = 0; reg < 4; ++reg)
                s[f][reg] += pb[reg] + pm[reg];
        }
        if (i < 15) {   // prefetch next tile's bias/mask (regs now consumed)
            #pragma unroll
            for (int f = 0; f < 4; ++f) {
                bv4[f] = *(const float4*)(bias + brow + s0 + 64 + f * 16 + l16 * 4);
                mv4[f] = *(const float4*)(mask + mrow + s0 + 64 + f * 16 + l16 * 4);
            }
        }

        // ---- online softmax (one q-row per thread) with defer-max (THR=8) ----
        float mx = s[0][0];
        #pragma unroll
        for (int f = 0; f < 4; ++f)
            #pragma unroll
            for (int reg = 0; reg < 4; ++reg)
                mx = fmaxf(mx, s[f][reg]);
        mx = fmaxf(mx, __shfl_xor(mx, 16));
        mx = fmaxf(mx, __shfl_xor(mx, 32));
        if (!__all(mx - m_run <= 8.f)) {
            float m_new = fmaxf(m_run, mx);
            float scv = __expf(m_run - m_new);
            l_run *= scv;
            m_run = m_new;
            float scq[4];
            #pragma unroll
            for (int reg = 0; reg < 4; ++reg) scq[reg] = __shfl(scv, l16 * 4 + reg);
            #pragma unroll
            for (int f = 0; f < 4; ++f)
                #pragma unroll
                for (int reg = 0; reg < 4; ++reg)
                    o[f][reg] *= scq[reg];
        }
        float psum = 0.f;
        #pragma unroll
        for (int f = 0; f < 4; ++f)
            #pragma unroll
            for (int reg = 0; reg < 4; ++reg) {
                float p = __expf(s[f][reg] - m_run);
                s[f][reg] = p; psum += p;
            }
        psum += __shfl_xor(psum, 16);
        psum += __shfl_xor(psum, 32);
        l_run += psum;

        // ---- P -> bf16 -> per-wave LDS slice [qlocal][key] ----
        #pragma unroll
        for (int f = 0; f < 4; ++f) {
            ushort4 pk;
            pk.x = f2bf(s[f][0]); pk.y = f2bf(s[f][1]);
            pk.z = f2bf(s[f][2]); pk.w = f2bf(s[f][3]);
            *(ushort4*)(Pw + l15 * 68 + f * 16 + l16 * 4) = pk;
        }
        __syncthreads();   // b2: Pw + Vtc ready for PV

        // ---- O += P @ V ----
        #pragma unroll
        for (int kc = 0; kc < 2; ++kc) {
            bf16x8 pf = *(const bf16x8*)(Pw + l15 * 68 + kc * 32 + l16 * 8);
            #pragma unroll
            for (int f = 0; f < 4; ++f) {
                bf16x8 vf = *(const bf16x8*)(Vtc + (f * 16 + l15) * 68 + kc * 32 + l16 * 8);
                o[f] = __builtin_amdgcn_mfma_f32_16x16x32_bf16(pf, vf, o[f], 0, 0, 0);
            }
        }
    }

    // ---- merge the two key-half partials ----
    __syncthreads();                    // all loop LDS use complete
    if (g == 1) {
        #pragma unroll
        for (int reg = 0; reg < 4; ++reg) {
            int qrow = wq * 16 + l16 * 4 + reg;
            #pragma unroll
            for (int f = 0; f < 4; ++f)
                Osh[qrow * 65 + f * 16 + l15] = o[f][reg];
        }
        if (l16 == 0) {
            Msh[wq * 16 + l15] = m_run;
            Lsh[wq * 16 + l15] = l_run;
        }
    }
    __syncthreads();
    if (g == 0) {
        #pragma unroll
        for (int reg = 0; reg < 4; ++reg) {
            int qrow = wq * 16 + l16 * 4 + reg;
            float m0 = __shfl(m_run, l16 * 4 + reg);
            float l0 = __shfl(l_run, l16 * 4 + reg);
            float m1 = Msh[qrow], l1 = Lsh[qrow];
            float M  = fmaxf(m0, m1);
            float a0 = __expf(m0 - M), a1 = __expf(m1 - M);
            float inv = 1.0f / (l0 * a0 + l1 * a1);
            int t = q0 + qrow;
            unsigned short* cb = ctx + ((size_t)b * T_ + t) * D_ + h * HD_;
            #pragma unroll
            for (int f = 0; f < 4; ++f) {
                float val = (o[f][reg] * a0 + Osh[qrow * 65 + f * 16 + l15] * a1) * inv;
                cb[f * 16 + l15] = f2bf(val);
            }
        }
    }
}

// ---------------------------------------------------------------------------
extern "C" void kernel_launch(void* const* d_in, const int* in_sizes, int n_in,
                              void* d_out, int out_size, void* d_ws, size_t ws_size,
                              hipStream_t stream) {
    const float* hs   = (const float*)d_in[0];
    const float* mask = (const float*)d_in[1];
    const float* bias = (const float*)d_in[2];
    const float* Wq   = (const float*)d_in[3];
    const float* bq   = (const float*)d_in[4];
    const float* Wk   = (const float*)d_in[5];
    const float* bk   = (const float*)d_in[6];
    const float* Wv   = (const float*)d_in[7];
    const float* bv   = (const float*)d_in[8];
    const float* Wo   = (const float*)d_in[9];
    const float* bo   = (const float*)d_in[10];
    float* out = (float*)d_out;

    const size_t NE = (size_t)B_ * T_ * D_;      // 3,145,728
    const size_t WE = (size_t)D_ * D_;           // 589,824
    unsigned short* ws = (unsigned short*)d_ws;
    unsigned short* hs_bf = ws;                  // NE
    unsigned short* wbf   = hs_bf + NE;          // 4*WE: Wq|Wk|Wv|Wo
    unsigned short* qkv   = wbf + 4 * WE;        // 3*NE: q|k|v in [B,H,T,HD]
    unsigned short* ctxb  = qkv + 3 * NE;        // NE

    cvt_f32_bf16<<<dim3(1536), 256, 0, stream>>>(hs, hs_bf, (int)(NE / 8));
    cvt_weights<<<dim3(288, 4), 256, 0, stream>>>(Wq, Wk, Wv, Wo, wbf, (int)(WE / 8));

    // fused QKV GEMM: N = 2304, grid 32 x 18
    gemm_bt_lds<<<dim3(32, 18), 256, 0, stream>>>(hs_bf, wbf, bq, bk, bv, qkv, 1);

    attn_fwd_mfma<<<dim3(T_ / 64, B_ * H_), 512, 0, stream>>>(
        qkv, qkv + NE, qkv + 2 * NE, bias, mask, ctxb);

    // out projection: W rows 2304..3071 of wbf
    gemm_bt_lds<<<dim3(32, 6), 256, 0, stream>>>(ctxb, wbf + 3 * WE, bo, nullptr, nullptr, out, 0);
}